// Round 2
// baseline (655.984 us; speedup 1.0000x reference)
//
#include <hip/hip_runtime.h>
#include <hip/hip_bf16.h>

typedef __attribute__((ext_vector_type(8))) short short8;
typedef __attribute__((ext_vector_type(4))) float f32x4;

#define NB   32
#define HH   112
#define WW   112
#define CIN  128
#define OH_  110
#define OW_  110
#define COUT 256
#define NTAP 9
#define M_TOTAL (NB * OH_ * OW_)   // 387200 = 3025 * 128

__device__ __forceinline__ unsigned short f2bf(float f) {
  union { float f; unsigned u; } v; v.f = f;
  unsigned r = v.u + 0x7fffu + ((v.u >> 16) & 1u);  // round-to-nearest-even
  return (unsigned short)(r >> 16);
}

// Binarize + pack weights per-MFMA-fragment.
// Output layout: frag[tap][nb(16)][kk(4)][lane(64)] of short8 (16 B), so one
// wave's fragment load is 64 lanes x 16 B = 1 KB contiguous & coalesced.
// Fragment semantics (matches compute): n = nb*16 + (lane&15),
// k = kk*32 + (lane>>4)*8 + j, j=0..7. Source kern is [tap][ci][co] = [tap][k][n].
__global__ void prep_weights(const float* __restrict__ kern, short8* __restrict__ bfrag) {
  int idx = blockIdx.x * 256 + threadIdx.x;   // 9*16*4*64 = 36864 total
  if (idx >= NTAP * 16 * 4 * 64) return;
  int lane = idx & 63;
  int kk   = (idx >> 6) & 3;
  int nb   = (idx >> 8) & 15;
  int tap  = idx >> 12;
  int n     = nb * 16 + (lane & 15);
  int kbase = kk * 32 + (lane >> 4) * 8;
  short8 v;
#pragma unroll
  for (int j = 0; j < 8; ++j) {
    float kv = kern[(tap * CIN + kbase + j) * COUT + n];
    // match reference bit-for-bit: hs = clip((k/H+1)/2,0,1); round-half-even
    float hs = fminf(fmaxf((kv + 1.0f) * 0.5f, 0.0f), 1.0f);
    float wb = 2.0f * rintf(hs) - 1.0f;   // {-1, +1}
    v[j] = (short)f2bf(wb);
  }
  bfrag[idx] = v;
}

__global__ __launch_bounds__(512, 4) void bconv(
    const float* __restrict__ x, const short8* __restrict__ bfrag,
    const float* __restrict__ bias, float* __restrict__ out) {
  __shared__ char ldsA[32768];   // 128 rows x 128 k bf16, XOR-swizzled

  const int tid  = threadIdx.x;
  const int lane = tid & 63;
  const int wave = tid >> 6;
  const int wm   = wave >> 2;   // 0..1
  const int wn   = wave & 3;    // 0..3
  const int m0   = blockIdx.x * 128;

  // Per-thread A staging addresses (row set is tap-invariant; tap adds xoff)
  const int c4 = tid & 31;               // float4 index within a 128-float row
  int abase[8];
  int awoff[8];
#pragma unroll
  for (int it = 0; it < 8; ++it) {
    int row = it * 16 + (tid >> 5);
    int m = m0 + row;
    int nimg = m / (OH_ * OW_);
    int r2 = m - nimg * (OH_ * OW_);
    int oh = r2 / OW_;
    int ow = r2 - oh * OW_;
    abase[it] = ((nimg * HH + oh) * WW + ow) * CIN + c4 * 4;
    awoff[it] = row * 256 + ((c4 * 8) ^ ((row & 7) << 4));
  }

  f32x4 acc[4][4];
#pragma unroll
  for (int i = 0; i < 4; ++i)
#pragma unroll
    for (int j = 0; j < 4; ++j) acc[i][j] = (f32x4){0.f, 0.f, 0.f, 0.f};

#pragma unroll 1
  for (int tap = 0; tap < NTAP; ++tap) {
    const int ky = tap / 3;
    const int kx = tap - ky * 3;
    const int xoff = (ky * WW + kx) * CIN;
    __syncthreads();
    // ---- Stage A: 128x128 fp32 -> bf16, swizzled LDS ----
#pragma unroll
    for (int it = 0; it < 8; ++it) {
      const float4 xv = *(const float4*)(x + abase[it] + xoff);
      ushort4 h;
      h.x = f2bf(xv.x); h.y = f2bf(xv.y); h.z = f2bf(xv.z); h.w = f2bf(xv.w);
      *(ushort4*)(ldsA + awoff[it]) = h;
    }
    __syncthreads();
    // ---- Compute: K=128 as 4 k-steps of 32; B fragments direct from L2 ----
    const short8* bt = bfrag + (((long)tap * 16 + wn * 4) << 8);  // *4kk*64lane
#pragma unroll
    for (int kk = 0; kk < 4; ++kk) {
      const int kb = kk * 64 + ((lane >> 4) << 4);
      short8 af[4], bf[4];
#pragma unroll
      for (int mi = 0; mi < 4; ++mi) {
        int row = wm * 64 + mi * 16 + (lane & 15);
        af[mi] = *(const short8*)(ldsA + row * 256 + (kb ^ ((row & 7) << 4)));
      }
#pragma unroll
      for (int ni = 0; ni < 4; ++ni)
        bf[ni] = bt[((ni << 2) + kk << 6) + lane];
#pragma unroll
      for (int mi = 0; mi < 4; ++mi)
#pragma unroll
        for (int ni = 0; ni < 4; ++ni)
          acc[mi][ni] = __builtin_amdgcn_mfma_f32_16x16x32_bf16(af[mi], bf[ni], acc[mi][ni], 0, 0, 0);
    }
  }

  // ---- Epilogue: C/D layout col=lane&15, row=(lane>>4)*4+reg ----
  const int  colb = wn * 64 + (lane & 15);
  const long rowb = (long)m0 + wm * 64 + ((lane >> 4) << 2);
#pragma unroll
  for (int ni = 0; ni < 4; ++ni) {
    const int col = colb + ni * 16;
    const float bv = bias[col];
#pragma unroll
    for (int mi = 0; mi < 4; ++mi) {
#pragma unroll
      for (int r = 0; r < 4; ++r) {
        out[(rowb + mi * 16 + r) * COUT + col] = acc[mi][ni][r] + bv;
      }
    }
  }
}

extern "C" void kernel_launch(void* const* d_in, const int* in_sizes, int n_in,
                              void* d_out, int out_size, void* d_ws, size_t ws_size,
                              hipStream_t stream) {
  const float* x    = (const float*)d_in[0];
  const float* kern = (const float*)d_in[1];
  const float* bias = (const float*)d_in[2];
  float* out = (float*)d_out;
  short8* bfrag = (short8*)d_ws;   // 9*16*4*64*16 B = 589824 B

  prep_weights<<<(NTAP * 16 * 4 * 64 + 255) / 256, 256, 0, stream>>>(kern, bfrag);
  bconv<<<dim3(M_TOTAL / 128), dim3(512), 0, stream>>>(x, bfrag, bias, out);
}

// Round 3
// 373.552 us; speedup vs baseline: 1.7561x; 1.7561x over previous
//
#include <hip/hip_runtime.h>
#include <hip/hip_bf16.h>

typedef __attribute__((ext_vector_type(8))) short short8;
typedef __attribute__((ext_vector_type(4))) float f32x4;

#define NB   32
#define HH   112
#define WW   112
#define CIN  128
#define OH_  110
#define OW_  110
#define COUT 256
#define NTAP 9
#define M_TOTAL (NB * OH_ * OW_)   // 387200 = 3025 * 128

__device__ __forceinline__ unsigned short f2bf(float f) {
  union { float f; unsigned u; } v; v.f = f;
  unsigned r = v.u + 0x7fffu + ((v.u >> 16) & 1u);  // round-to-nearest-even
  return (unsigned short)(r >> 16);
}

// Binarize + pack weights per-MFMA-fragment, in the exact order the conv
// kernel's waves consume them from LDS (linear global_load_lds copy).
// chunk idx = ((tap*16 + nb)*4 + kk)*64 + lane, 16 B each.
// Fragment semantics: n = nb*16 + (lane&15), k = kk*32 + (lane>>4)*8 + j.
__global__ void prep_weights(const float* __restrict__ kern, short8* __restrict__ bfrag) {
  int idx = blockIdx.x * 256 + threadIdx.x;   // 9*16*4*64 = 36864 total
  if (idx >= NTAP * 16 * 4 * 64) return;
  int lane = idx & 63;
  int kk   = (idx >> 6) & 3;
  int nb   = (idx >> 8) & 15;
  int tap  = idx >> 12;
  int n     = nb * 16 + (lane & 15);
  int kbase = kk * 32 + (lane >> 4) * 8;
  short8 v;
#pragma unroll
  for (int j = 0; j < 8; ++j) {
    float kv = kern[(tap * CIN + kbase + j) * COUT + n];
    float hs = fminf(fmaxf((kv + 1.0f) * 0.5f, 0.0f), 1.0f);
    float wb = 2.0f * rintf(hs) - 1.0f;   // {-1, +1}, round-half-even like jnp.round
    v[j] = (short)f2bf(wb);
  }
  bfrag[idx] = v;
}

__device__ __forceinline__ void gload16(const char* g, char* l) {
  __builtin_amdgcn_global_load_lds(
      (const __attribute__((address_space(1))) unsigned int*)g,
      (__attribute__((address_space(3))) unsigned int*)l, 16, 0, 0);
}

__global__ __launch_bounds__(512, 2) void bconv(
    const float* __restrict__ x, const char* __restrict__ bfragB,
    const float* __restrict__ bias, float* __restrict__ out) {
  extern __shared__ char lds[];
  char* bufA  = lds;                       // 32 KB: A 128x128 bf16, XOR-swizzled
  char* bufB0 = lds + 32768;               // 64 KB: B tap buffer 0 (fragment-linear)
  char* bufB1 = lds + 98304;               // 64 KB: B tap buffer 1

  const int tid  = threadIdx.x;
  const int lane = tid & 63;
  const int wave = tid >> 6;
  const int wm   = wave >> 2;   // 0..1
  const int wn   = wave & 3;    // 0..3
  const int m0   = blockIdx.x * 128;

  // ---- A staging addresses (tap-invariant base; tap adds xoff) ----
  const int c4 = tid & 31;               // float4 index within a 128-float row
  int abase[8];
  int awoff[8];
#pragma unroll
  for (int it = 0; it < 8; ++it) {
    int row = it * 16 + (tid >> 5);
    int m = m0 + row;
    int nimg = m / (OH_ * OW_);
    int r2 = m - nimg * (OH_ * OW_);
    int oh = r2 / OW_;
    int ow = r2 - oh * OW_;
    abase[it] = ((nimg * HH + oh) * WW + ow) * CIN + c4 * 4;
    awoff[it] = row * 256 + ((c4 * 8) ^ ((row & 7) << 4));
  }

  // ---- fragment read addressing ----
  const int aswz  = (lane & 7) << 4;          // row&7 == lane&7 for A frag rows
  const int klane = (lane >> 4) << 4;
  int arow[4];
#pragma unroll
  for (int mi = 0; mi < 4; ++mi) arow[mi] = (wm * 64 + mi * 16 + (lane & 15)) * 256;
  const int bstg = wave * 1024 + lane * 16;   // B staging slice for this wave

  f32x4 acc[4][4];
#pragma unroll
  for (int i = 0; i < 4; ++i)
#pragma unroll
    for (int j = 0; j < 4; ++j) acc[i][j] = (f32x4){0.f, 0.f, 0.f, 0.f};

  // ---- prologue: issue tap-0 A (to regs) and B (to LDS buf0) ----
  float4 av[8];
#pragma unroll
  for (int it = 0; it < 8; ++it) av[it] = *(const float4*)(x + abase[it]);
#pragma unroll
  for (int i = 0; i < 8; ++i)
    gload16(bfragB + i * 8192 + bstg, bufB0 + i * 8192 + bstg);

#pragma unroll 1
  for (int t = 0; t < NTAP; ++t) {
    // tap boundary: this tap's A regs + B LDS arrivals complete; all waves
    // finished reading bufA (prev tap) before we overwrite it.
    asm volatile("s_waitcnt vmcnt(0)" ::: "memory");
    __builtin_amdgcn_s_barrier();
    // write A tile (cvt fp32->bf16), swizzled
#pragma unroll
    for (int it = 0; it < 8; ++it) {
      ushort4 h;
      h.x = f2bf(av[it].x); h.y = f2bf(av[it].y);
      h.z = f2bf(av[it].z); h.w = f2bf(av[it].w);
      *(ushort4*)(bufA + awoff[it]) = h;
    }
    asm volatile("s_waitcnt lgkmcnt(0)" ::: "memory");
    __builtin_amdgcn_s_barrier();

    const int tn = t + 1;
    const int xoffn = ((tn / 3) * WW + (tn % 3)) * CIN;
    const char* bsrcT = bfragB + ((long)tn << 16);
    char* bdstT = (tn & 1) ? bufB1 : bufB0;
    const char* bcur = (t & 1) ? bufB1 : bufB0;

#pragma unroll
    for (int kk = 0; kk < 4; ++kk) {
      // prefetch tap t+1: 2 B gload_lds + 2 A fp32 loads per phase
      if (t < NTAP - 1) {
        gload16(bsrcT + (2 * kk) * 8192 + bstg, bdstT + (2 * kk) * 8192 + bstg);
        gload16(bsrcT + (2 * kk + 1) * 8192 + bstg, bdstT + (2 * kk + 1) * 8192 + bstg);
        av[2 * kk]     = *(const float4*)(x + abase[2 * kk] + xoffn);
        av[2 * kk + 1] = *(const float4*)(x + abase[2 * kk + 1] + xoffn);
      }
      // ds-read this phase's fragments
      short8 af[4], bfr[4];
      const int kb = (kk * 64 + klane) ^ aswz;
#pragma unroll
      for (int mi = 0; mi < 4; ++mi)
        af[mi] = *(const short8*)(bufA + arow[mi] + kb);
#pragma unroll
      for (int ni = 0; ni < 4; ++ni)
        bfr[ni] = *(const short8*)(bcur + ((((wn * 4 + ni) * 4 + kk) << 10) + lane * 16));
      __builtin_amdgcn_s_barrier();
      asm volatile("s_waitcnt lgkmcnt(0)" ::: "memory");
      __builtin_amdgcn_sched_barrier(0);
      __builtin_amdgcn_s_setprio(1);
#pragma unroll
      for (int mi = 0; mi < 4; ++mi)
#pragma unroll
        for (int ni = 0; ni < 4; ++ni)
          acc[mi][ni] = __builtin_amdgcn_mfma_f32_16x16x32_bf16(af[mi], bfr[ni], acc[mi][ni], 0, 0, 0);
      __builtin_amdgcn_s_setprio(0);
      __builtin_amdgcn_s_barrier();
    }
  }

  // ---- Epilogue: C/D layout col=lane&15, row=(lane>>4)*4+reg ----
  const int  colb = wn * 64 + (lane & 15);
  const long rowb = (long)m0 + wm * 64 + ((lane >> 4) << 2);
#pragma unroll
  for (int ni = 0; ni < 4; ++ni) {
    const int col = colb + ni * 16;
    const float bv = bias[col];
#pragma unroll
    for (int mi = 0; mi < 4; ++mi) {
#pragma unroll
      for (int r = 0; r < 4; ++r) {
        out[(rowb + mi * 16 + r) * COUT + col] = acc[mi][ni][r] + bv;
      }
    }
  }
}

extern "C" void kernel_launch(void* const* d_in, const int* in_sizes, int n_in,
                              void* d_out, int out_size, void* d_ws, size_t ws_size,
                              hipStream_t stream) {
  const float* x    = (const float*)d_in[0];
  const float* kern = (const float*)d_in[1];
  const float* bias = (const float*)d_in[2];
  float* out = (float*)d_out;
  short8* bfrag = (short8*)d_ws;   // 9*16*4*64*16 B = 589824 B

  (void)hipFuncSetAttribute((const void*)bconv,
                            hipFuncAttributeMaxDynamicSharedMemorySize, 163840);

  prep_weights<<<(NTAP * 16 * 4 * 64 + 255) / 256, 256, 0, stream>>>(kern, bfrag);
  bconv<<<dim3(M_TOTAL / 128), dim3(512), 163840, stream>>>(x, (const char*)bfrag, bias, out);
}